// Round 6
// baseline (360.602 us; speedup 1.0000x reference)
//
#include <hip/hip_runtime.h>

#define N 1024
#define NN (N * N)
#define STRIPS 5           // 5 waves x 248 valid cols >= 1024  (4 cols/lane)
#define SEGS 64            // 64 * 16 = 1024 rows
#define SEGROWS 16
#define NUNITS (STRIPS * SEGS * 8)   // 2560 wave-units
#define NBLOCKS (NUNITS / 4)         // 640 four-wave blocks

__device__ __forceinline__ int refl(int i) {   // reflect-101
    if (i < 0) return -i;
    if (i >= N) return 2 * N - 2 - i;
    return i;
}

// One image's pipeline step at row yv, 4 columns per lane.
// Per-column arithmetic is expression-identical to the verified 1-col kernel;
// horizontal halo comes from 10 shuffles per row instead of 10 per column.
// STAGE: 0=load+hblur, 1=+vblur, 2=+sobel/mag/axis, 3=+NMS (returns 4-bit edge mask).
template<bool COLE, bool ROWE, int STAGE>
static __device__ __forceinline__ int img_row(
    int yv, float g0, float g1, float g2, float g3,
    float (&h)[4][5], float (&bl)[4][3], float (&mg)[4][3],
    float (&mL)[3], float (&mR)[3], int (&ax)[4], int (&axU)[4],
    bool cz0, bool czN, int iL1, int iR1)
{
    const float w0 = 0.05448868f, w1 = 0.24420134f, w2 = 0.40261996f,
                w3 = 0.24420134f, w4 = 0.05448868f;

    // gray halo: cols c0-2, c0-1 from left lane; c0+4, c0+5 from right lane
    float gm2 = __shfl(g2, iL1, 64), gm1 = __shfl(g3, iL1, 64);
    float gp4 = __shfl(g0, iR1, 64), gp5 = __shfl(g1, iR1, 64);
    float hn0 = w0*gm2 + w1*gm1 + w2*g0 + w3*g1 + w4*g2;
    float hn1 = w0*gm1 + w1*g0 + w2*g1 + w3*g2 + w4*g3;
    float hn2 = w0*g0  + w1*g1 + w2*g2 + w3*g3 + w4*gp4;
    float hn3 = w0*g1  + w1*g2 + w2*g3 + w3*gp4 + w4*gp5;
#pragma unroll
    for (int j = 0; j < 4; ++j) {
#pragma unroll
        for (int k = 0; k < 4; ++k) h[j][k] = h[j][k+1];
    }
    h[0][4]=hn0; h[1][4]=hn1; h[2][4]=hn2; h[3][4]=hn3;
    if (STAGE < 1) return 0;

    float bn[4];
#pragma unroll
    for (int j = 0; j < 4; ++j)
        bn[j] = w0*h[j][0] + w1*h[j][1] + w2*h[j][2] + w3*h[j][3] + w4*h[j][4];
#pragma unroll
    for (int j = 0; j < 4; ++j) { bl[j][0]=bl[j][1]; bl[j][1]=bl[j][2]; bl[j][2]=bn[j]; }
    if (STAGE < 2) return 0;

    // Sobel at row z = yv-3
    float s[4], d[4];
#pragma unroll
    for (int j = 0; j < 4; ++j) {
        float A_, C_;
        if (ROWE) {
            int z = yv - 3;
            A_ = (z == 0)     ? bl[j][1] : bl[j][0];
            C_ = (z == N - 1) ? bl[j][1] : bl[j][2];
        } else { A_ = bl[j][0]; C_ = bl[j][2]; }
        s[j] = A_ + 2.f*bl[j][1] + C_;
        d[j] = C_ - A_;
    }
    float sL = __shfl(s[3], iL1, 64), dL = __shfl(d[3], iL1, 64);
    float sR = __shfl(s[0], iR1, 64), dR = __shfl(d[0], iR1, 64);
    if (COLE) {
        sL = cz0 ? s[0] : sL;  dL = cz0 ? d[0] : dL;
        sR = czN ? s[3] : sR;  dR = czN ? d[3] : dR;
    }
    float gx[4], gy[4];
    gx[0] = s[1] - sL;   gy[0] = dL + 2.f*d[0] + d[1];
    gx[1] = s[2] - s[0]; gy[1] = d[0] + 2.f*d[1] + d[2];
    gx[2] = s[3] - s[1]; gy[2] = d[1] + 2.f*d[2] + d[3];
    gx[3] = sR - s[2];   gy[3] = d[2] + 2.f*d[3] + dR;

    float m[4]; int cd[4];
#pragma unroll
    for (int j = 0; j < 4; ++j) {
        m[j] = sqrtf(gx[j]*gx[j] + gy[j]*gy[j] + 1e-6f);
        float ax_ = fabsf(gx[j]), ay_ = fabsf(gy[j]);
        cd[j] = (ay_ <= 0.41421356f * ax_) ? 0
              : (ay_ >= 2.41421356f * ax_) ? 1
              : (((gx[j] > 0.f) == (gy[j] > 0.f)) ? 2 : 3);
    }
    float mLn = __shfl(m[3], iL1, 64);
    float mRn = __shfl(m[0], iR1, 64);
    if (COLE) { mLn = cz0 ? 0.f : mLn;  mRn = czN ? 0.f : mRn; }
#pragma unroll
    for (int j = 0; j < 4; ++j) { mg[j][0]=mg[j][1]; mg[j][1]=mg[j][2]; mg[j][2]=m[j]; }
    mL[0]=mL[1]; mL[1]=mL[2]; mL[2]=mLn;
    mR[0]=mR[1]; mR[1]=mR[2]; mR[2]=mRn;
#pragma unroll
    for (int j = 0; j < 4; ++j) { axU[j] = ax[j]; ax[j] = cd[j]; }
    if (STAGE < 3) return 0;

    // NMS at row w = yv-4; column windows -1..4 as arrays (indices all literal)
    float rm1[6] = { mL[0], mg[0][0], mg[1][0], mg[2][0], mg[3][0], mR[0] };
    float rc [6] = { mL[1], mg[0][1], mg[1][1], mg[2][1], mg[3][1], mR[1] };
    float rp1[6] = { mL[2], mg[0][2], mg[1][2], mg[2][2], mg[3][2], mR[2] };
    if (ROWE) {
        int w = yv - 4;
        if (w == 0) {
#pragma unroll
            for (int j = 0; j < 6; ++j) rm1[j] = 0.f;
        }
        if (w == N - 1) {
#pragma unroll
            for (int j = 0; j < 6; ++j) rp1[j] = 0.f;
        }
    }
    int em = 0;
#pragma unroll
    for (int j = 1; j <= 4; ++j) {
        int a_ = axU[j-1];
        float n1 = (a_ == 0) ? rc[j+1] : (a_ == 1) ? rm1[j] : (a_ == 2) ? rm1[j+1] : rm1[j-1];
        float n2 = (a_ == 0) ? rc[j-1] : (a_ == 1) ? rp1[j] : (a_ == 2) ? rp1[j-1] : rp1[j+1];
        bool e = (rc[j] > n1) && (rc[j] > n2) && (rc[j] > 0.1f);
        em |= (int)e << (j-1);
    }
    return em;
}

// Load row rrv into double-buffer slot k (k literal). Interior: 6 float4.
// COLE: 24 scalar loads through per-column reflected offsets.
#define LOADROW(k, rrv) { size_t o_ = (size_t)(rrv) * N;                          \
    if (!COLE) {                                                                  \
      vAr##k = *(const float4*)(Ar + o_); vAg##k = *(const float4*)(Ag + o_);     \
      vAb##k = *(const float4*)(Ab + o_);                                         \
      vBr##k = *(const float4*)(Br + o_); vBg##k = *(const float4*)(Bg + o_);     \
      vBb##k = *(const float4*)(Bb + o_);                                         \
    } else {                                                                      \
      vAr##k.x = Ar[o_+rq0]; vAr##k.y = Ar[o_+rq1]; vAr##k.z = Ar[o_+rq2]; vAr##k.w = Ar[o_+rq3]; \
      vAg##k.x = Ag[o_+rq0]; vAg##k.y = Ag[o_+rq1]; vAg##k.z = Ag[o_+rq2]; vAg##k.w = Ag[o_+rq3]; \
      vAb##k.x = Ab[o_+rq0]; vAb##k.y = Ab[o_+rq1]; vAb##k.z = Ab[o_+rq2]; vAb##k.w = Ab[o_+rq3]; \
      vBr##k.x = Br[o_+rq0]; vBr##k.y = Br[o_+rq1]; vBr##k.z = Br[o_+rq2]; vBr##k.w = Br[o_+rq3]; \
      vBg##k.x = Bg[o_+rq0]; vBg##k.y = Bg[o_+rq1]; vBg##k.z = Bg[o_+rq2]; vBg##k.w = Bg[o_+rq3]; \
      vBb##k.x = Bb[o_+rq0]; vBb##k.y = Bb[o_+rq1]; vBb##k.z = Bb[o_+rq2]; vBb##k.w = Bb[o_+rq3]; \
    } }

#define BODY(yv, STAGE, kb, RELOAD) {                                             \
    float ga0 = 0.299f*vAr##kb.x + 0.587f*vAg##kb.x + 0.114f*vAb##kb.x;           \
    float ga1 = 0.299f*vAr##kb.y + 0.587f*vAg##kb.y + 0.114f*vAb##kb.y;           \
    float ga2 = 0.299f*vAr##kb.z + 0.587f*vAg##kb.z + 0.114f*vAb##kb.z;           \
    float ga3 = 0.299f*vAr##kb.w + 0.587f*vAg##kb.w + 0.114f*vAb##kb.w;           \
    float gb0 = 0.299f*vBr##kb.x + 0.587f*vBg##kb.x + 0.114f*vBb##kb.x;           \
    float gb1 = 0.299f*vBr##kb.y + 0.587f*vBg##kb.y + 0.114f*vBb##kb.y;           \
    float gb2 = 0.299f*vBr##kb.z + 0.587f*vBg##kb.z + 0.114f*vBb##kb.z;           \
    float gb3 = 0.299f*vBr##kb.w + 0.587f*vBg##kb.w + 0.114f*vBb##kb.w;           \
    if (RELOAD) { int n_ = (yv) + 2; int r_ = ROWE ? refl(n_) : (n_);             \
                  LOADROW(kb, r_) }                                               \
    int emA = img_row<COLE,ROWE,STAGE>((yv), ga0,ga1,ga2,ga3,                     \
                  ah,abl,amg,amL,amR,aax,aaxU, cz0,czN,iL1,iR1);                  \
    int emB = img_row<COLE,ROWE,STAGE>((yv), gb0,gb1,gb2,gb3,                     \
                  bh,bbl,bmg,bmL,bmR,bax,baxU, cz0,czN,iL1,iR1);                  \
    if ((STAGE) >= 3) acc += valid ? __popc(emA ^ emB) : 0;                       \
  }

template<bool COLE, bool ROWE>
__device__ __forceinline__ void edge_unit(
    const float* __restrict__ op, const float* __restrict__ gt,
    unsigned int* __restrict__ partials,
    int unit, int img, int strip, int seg, int lane)
{
    const int cb = strip * 248 - 4;
    const int c0 = cb + 4 * lane;            // lane's first col; c0 % 4 == 0

    // reflected per-column offsets (COLE strips only; strip 0 cols <0,
    // strip 4 cols >=1024 load their reflect-101 partners)
    int rq0 = 0, rq1 = 0, rq2 = 0, rq3 = 0;
    if (COLE) { rq0 = refl(c0); rq1 = refl(c0+1); rq2 = refl(c0+2); rq3 = refl(c0+3); }

    const float* Ar = op + (size_t)img * 3 * NN + (COLE ? 0 : c0);
    const float* Ag = Ar + NN;
    const float* Ab = Ar + 2 * NN;
    const float* Br = gt + (size_t)img * 3 * NN + (COLE ? 0 : c0);
    const float* Bg = Br + NN;
    const float* Bb = Br + 2 * NN;

    // c0 % 4 == 0  =>  image col 0 can only be a lane's col 0, col 1023 only col 3
    const bool cz0 = COLE && (c0 == 0);
    const bool czN = COLE && (c0 + 3 == N - 1);
    const bool valid = (lane >= 1) && (lane <= 62) &&
                       (!COLE || ((c0 >= 0) && (c0 + 3 < N)));

    const int iL1 = lane - 1, iR1 = lane + 1;

    // rolling windows, 4 cols per image (all indices literal after unroll)
    float ah[4][5] = {}, bh[4][5] = {};
    float abl[4][3] = {}, bbl[4][3] = {};
    float amg[4][3] = {}, bmg[4][3] = {};
    float amL[3] = {}, amR[3] = {}, bmL[3] = {}, bmR[3] = {};
    int aax[4] = {}, aaxU[4] = {}, bax[4] = {}, baxU[4] = {};

    // 2-deep double-buffered row prefetch (load->use distance = 2 row-iters)
    float4 vAr0, vAg0, vAb0, vBr0, vBg0, vBb0;
    float4 vAr1, vAg1, vAb1, vBr1, vBg1, vBb1;

    int acc = 0;
    const int R0 = seg * SEGROWS;

    if (!ROWE) {
        LOADROW(0, R0 - 4) LOADROW(1, R0 - 3)
        // staged priming: exact dataflow subset (schedule verified in round 4)
        BODY(R0 - 4, 0, 0, 1) BODY(R0 - 3, 0, 1, 1)
        BODY(R0 - 2, 0, 0, 1) BODY(R0 - 1, 0, 1, 1)
        BODY(R0,     1, 0, 1) BODY(R0 + 1, 1, 1, 1)
        BODY(R0 + 2, 2, 0, 1) BODY(R0 + 3, 2, 1, 1)
    } else {
        LOADROW(0, refl(R0 - 4)) LOADROW(1, refl(R0 - 3))
        // row-edge segs: full stage-2 priming (matches verified kernel)
        BODY(R0 - 4, 2, 0, 1) BODY(R0 - 3, 2, 1, 1)
        BODY(R0 - 2, 2, 0, 1) BODY(R0 - 1, 2, 1, 1)
        BODY(R0,     2, 0, 1) BODY(R0 + 1, 2, 1, 1)
        BODY(R0 + 2, 2, 0, 1) BODY(R0 + 3, 2, 1, 1)
    }

    // 16 output rows: 14 with reload, last 2 without
#pragma unroll 1
    for (int t = 0; t < 7; ++t) {
        int y = R0 + 4 + 2 * t;
        BODY(y,     3, 0, 1)
        BODY(y + 1, 3, 1, 1)
    }
    BODY(R0 + SEGROWS + 2, 3, 0, 0)
    BODY(R0 + SEGROWS + 3, 3, 1, 0)

    for (int off = 32; off > 0; off >>= 1)
        acc += __shfl_down(acc, off, 64);
    if (lane == 0)
        partials[unit] = (unsigned int)acc;
}

__global__ __launch_bounds__(256)
void edge_diff_kernel(const float* __restrict__ op, const float* __restrict__ gt,
                      unsigned int* __restrict__ partials)
{
    int lane = threadIdx.x & 63;
    // IDENTITY unit order (seg fastest) — the verified low-FETCH scan order.
    int unit = blockIdx.x * 4 + (threadIdx.x >> 6);
    int img  = unit / (STRIPS * SEGS);
    int rem  = unit - img * (STRIPS * SEGS);
    int strip = rem >> 6;            // SEGS = 64
    int seg   = rem & (SEGS - 1);

    bool cole = (strip == 0) || (strip == STRIPS - 1);
    bool rowe = (seg == 0)   || (seg == SEGS - 1);

    if (!cole) {
        if (!rowe) edge_unit<false, false>(op, gt, partials, unit, img, strip, seg, lane);
        else       edge_unit<false, true >(op, gt, partials, unit, img, strip, seg, lane);
    } else {
        if (!rowe) edge_unit<true,  false>(op, gt, partials, unit, img, strip, seg, lane);
        else       edge_unit<true,  true >(op, gt, partials, unit, img, strip, seg, lane);
    }
}

__global__ __launch_bounds__(256)
void finalize_kernel(const unsigned int* __restrict__ partials, float* __restrict__ out)
{
    __shared__ unsigned int ws[4];
    int tid = threadIdx.x;
    unsigned int sum = 0;
    for (int i = tid; i < NUNITS; i += 256)
        sum += partials[i];
    int d = (int)sum;
    for (int off = 32; off > 0; off >>= 1)
        d += __shfl_down(d, off, 64);
    if ((tid & 63) == 0) ws[tid >> 6] = (unsigned int)d;
    __syncthreads();
    if (tid == 0)
        out[0] = (float)(ws[0] + ws[1] + ws[2] + ws[3]) / 8388608.0f;  // 8*1024*1024
}

extern "C" void kernel_launch(void* const* d_in, const int* in_sizes, int n_in,
                              void* d_out, int out_size, void* d_ws, size_t ws_size,
                              hipStream_t stream)
{
    const float* op = (const float*)d_in[0];
    const float* gt = (const float*)d_in[1];
    unsigned int* partials = (unsigned int*)d_ws;   // NUNITS uints, fully overwritten

    edge_diff_kernel<<<dim3(NBLOCKS), dim3(256), 0, stream>>>(op, gt, partials);
    finalize_kernel<<<1, dim3(256), 0, stream>>>(partials, (float*)d_out);
}